// Round 9
// baseline (391.444 us; speedup 1.0000x reference)
//
#include <hip/hip_runtime.h>
#include <hip/hip_bf16.h>
#include <cstdint>

#define T_DIM 2048
#define B_DIM 2
#define E_DIM 1024
#define H_DIM 16
#define HD_DIM 64
#define M_DIM 4096          // T*B rows
#define N1_DIM 3072         // 3*E
#define QK_SCALE 0.125f     // HD^-0.5

typedef __attribute__((ext_vector_type(8))) short bfrag;   // 8 x bf16 (4 VGPRs)
typedef __attribute__((ext_vector_type(4))) short short4v;
typedef __attribute__((ext_vector_type(4))) float f32x4;

__device__ __forceinline__ short f2bf(float f) {
  union { float f; uint32_t u; } v; v.f = f;
  uint32_t r = v.u + 0x7fffu + ((v.u >> 16) & 1u);   // RNE
  return (short)(r >> 16);
}
__device__ __forceinline__ float bf2f(short b) {
  union { uint32_t u; float f; } v; v.u = ((uint32_t)(uint16_t)b) << 16;
  return v.f;
}
__device__ __forceinline__ f32x4 mfma16(bfrag a, bfrag b, f32x4 c) {
  return __builtin_amdgcn_mfma_f32_16x16x32_bf16(a, b, c, 0, 0, 0);
}
// async global->LDS, 16B per lane, dest = uniform base + lane*16
__device__ __forceinline__ void gload16(const short* g, short* l) {
  __builtin_amdgcn_global_load_lds(
      (const __attribute__((address_space(1))) unsigned int*)g,
      (__attribute__((address_space(3))) unsigned int*)l, 16, 0, 0);
}

// ---------------- fused fp32 -> bf16 hi/lo split (x, w1, w2 in one launch) ----------------
__global__ void split3_kernel(
    const float* __restrict__ x,  const float* __restrict__ w1, const float* __restrict__ w2,
    short* __restrict__ xh,  short* __restrict__ xl,
    short* __restrict__ w1h, short* __restrict__ w1l,
    short* __restrict__ w2h, short* __restrict__ w2l)
{
  constexpr int NA = M_DIM * E_DIM;       // 4.19M
  constexpr int NB = N1_DIM * E_DIM;      // 3.15M
  constexpr int NC = E_DIM * E_DIM;       // 1.05M
  constexpr int TOT4 = (NA + NB + NC) >> 2;
  int t = blockIdx.x * blockDim.x + threadIdx.x;
  const int stride = gridDim.x * blockDim.x;
  for (; t < TOT4; t += stride) {
    int i = t << 2;
    const float* s; short* dh; short* dl;
    if (i < NA)            { s = x;  dh = xh;  dl = xl; }
    else if (i < NA + NB)  { i -= NA;       s = w1; dh = w1h; dl = w1l; }
    else                   { i -= NA + NB;  s = w2; dh = w2h; dl = w2l; }
    float4 v = *(const float4*)(s + i);
    short4v h, l;
    float vv[4] = {v.x, v.y, v.z, v.w};
#pragma unroll
    for (int c = 0; c < 4; ++c) {
      short hb = f2bf(vv[c]);
      h[c] = hb;
      l[c] = f2bf(vv[c] - bf2f(hb));
    }
    *(short4v*)(dh + i) = h;
    *(short4v*)(dl + i) = l;
  }
}

// ---------------- split-bf16 GEMM v2: global_load_lds staging ----------------
// C[m,n] = sum_k A[m,k]*B[n,k] + bias[n]; 3-term hi/lo correction.
// 128x128 tile, BK=32, 4 waves. Linear LDS [128][32] per plane, staged via
// global_load_lds dwordx4 (wave w stages rows [32w,32w+32): lane l -> row
// 32w+16j+(l>>2), 16B-slot l&3 — matches HW base+lane*16 write order).
// Two barriers per K-step (m97 structure; __syncthreads drains vmcnt).
template<int N_T, int K_T, bool OUT_BF16, bool DO_SCALE>
__global__ __launch_bounds__(256) void gemm_split(
    const short* __restrict__ Ahi, const short* __restrict__ Alo,
    const short* __restrict__ Bhi, const short* __restrict__ Blo,
    const float* __restrict__ bias, void* __restrict__ Cout)
{
  __shared__ short As[2][128][32];   // [hi/lo][row][k]
  __shared__ short Bs[2][128][32];

  const int m0 = blockIdx.y * 128;
  const int n0 = blockIdx.x * 128;
  const int tid = threadIdx.x;
  const int lane = tid & 63;
  const int wave = tid >> 6;
  const int wr = (wave >> 1) * 64;
  const int wc = (wave & 1) * 64;

  f32x4 acc[4][4];
#pragma unroll
  for (int i = 0; i < 4; ++i)
#pragma unroll
    for (int j = 0; j < 4; ++j) acc[i][j] = f32x4{0.f, 0.f, 0.f, 0.f};

  const int srow = (wave << 5) + (lane >> 2);   // staging row (j=0); +16 for j=1
  const int scol = (lane & 3) << 3;             // staging col (shorts)
  const int fr = lane & 15;
  const int fk = (lane >> 4) << 3;

  for (int k0 = 0; k0 < K_T; k0 += 32) {
    const size_t abase = (size_t)(m0 + srow) * K_T + k0 + scol;
    const size_t bbase = (size_t)(n0 + srow) * K_T + k0 + scol;
    __syncthreads();   // previous iter's ds_reads done before DMA overwrites
    gload16(Ahi + abase,                    &As[0][(wave << 5)][0]);
    gload16(Ahi + abase + (size_t)16 * K_T, &As[0][(wave << 5) + 16][0]);
    gload16(Alo + abase,                    &As[1][(wave << 5)][0]);
    gload16(Alo + abase + (size_t)16 * K_T, &As[1][(wave << 5) + 16][0]);
    gload16(Bhi + bbase,                    &Bs[0][(wave << 5)][0]);
    gload16(Bhi + bbase + (size_t)16 * K_T, &Bs[0][(wave << 5) + 16][0]);
    gload16(Blo + bbase,                    &Bs[1][(wave << 5)][0]);
    gload16(Blo + bbase + (size_t)16 * K_T, &Bs[1][(wave << 5) + 16][0]);
    __syncthreads();   // vmcnt(0) drained -> tiles visible

    bfrag afh[4], afl[4];
#pragma unroll
    for (int fi = 0; fi < 4; ++fi) {
      afh[fi] = *(const bfrag*)&As[0][wr + fi * 16 + fr][fk];
      afl[fi] = *(const bfrag*)&As[1][wr + fi * 16 + fr][fk];
    }
#pragma unroll
    for (int fj = 0; fj < 4; ++fj) {
      bfrag bfh = *(const bfrag*)&Bs[0][wc + fj * 16 + fr][fk];
      bfrag bfl = *(const bfrag*)&Bs[1][wc + fj * 16 + fr][fk];
#pragma unroll
      for (int fi = 0; fi < 4; ++fi) {
        acc[fi][fj] = mfma16(afh[fi], bfh, acc[fi][fj]);
        acc[fi][fj] = mfma16(afh[fi], bfl, acc[fi][fj]);
        acc[fi][fj] = mfma16(afl[fi], bfh, acc[fi][fj]);
      }
    }
  }

  // epilogue: C/D layout col=lane&15, row=(lane>>4)*4+r  [m89]
  const int cr = (lane >> 4) << 2;
  const int cc = lane & 15;
#pragma unroll
  for (int fi = 0; fi < 4; ++fi)
#pragma unroll
    for (int fj = 0; fj < 4; ++fj)
#pragma unroll
      for (int r = 0; r < 4; ++r) {
        int m = m0 + wr + fi * 16 + cr + r;
        int n = n0 + wc + fj * 16 + cc;
        float v = acc[fi][fj][r] + bias[n];
        if (DO_SCALE) { if (n < E_DIM) v *= QK_SCALE; }   // scale q only
        if (OUT_BF16) ((short*)Cout)[(size_t)m * N_T + n] = f2bf(v);
        else          ((float*)Cout)[(size_t)m * N_T + n] = v;
      }
}

// ---------------- fused attention v3 (unchanged — measured good in round 6) ----------------
__global__ __launch_bounds__(256) void attn_kernel(
    const short* __restrict__ qkv,   // [4096][3072] bf16 (q|k|v), q pre-scaled
    float* __restrict__ linv_ws,     // [B,H,T] reciprocal row sums
    short* __restrict__ ctx_hi, short* __restrict__ ctx_lo)  // [4096][1024]
{
  __shared__ short Ks[2][64][72];
  __shared__ short Vt[2][64][72];   // swizzled transpose
  __shared__ short Ps[128][76];

  const int bh = blockIdx.x;          // b*16 + h
  const int b  = bh >> 4;
  const int h  = bh & 15;
  const int t0 = blockIdx.y * 128;
  const int tid  = threadIdx.x;
  const int lane = tid & 63;
  const int wave = tid >> 6;
  const int fr = lane & 15;
  const int fk = (lane >> 4) << 3;
  const int cr = (lane >> 4) << 2;

  bfrag aq[2][2];
#pragma unroll
  for (int hh = 0; hh < 2; ++hh) {
    const size_t qb = ((size_t)(t0 + 32 * wave + 16 * hh + fr) * B_DIM + b) * N1_DIM + h * HD_DIM;
    aq[hh][0] = *(const bfrag*)(qkv + qb + fk);
    aq[hh][1] = *(const bfrag*)(qkv + qb + fk + 32);
  }

  bfrag ones;
#pragma unroll
  for (int j = 0; j < 8; ++j) ones[j] = (short)0x3F80;   // bf16 1.0

  f32x4 pv[2][4];
  f32x4 pvsum[2];
#pragma unroll
  for (int hh = 0; hh < 2; ++hh) {
    pvsum[hh] = f32x4{0.f, 0.f, 0.f, 0.f};
#pragma unroll
    for (int fd = 0; fd < 4; ++fd) pv[hh][fd] = f32x4{0.f, 0.f, 0.f, 0.f};
  }

  const int r  = tid >> 2;           // 0..63
  const int ds = (tid & 3) << 4;     // 0,16,32,48
  const int vc0 = (((r >> 3) ^ (ds >> 3)) << 3) | (r & 7);
  const int vc1 = (((r >> 3) ^ ((ds >> 3) + 1)) << 3) | (r & 7);

  constexpr int NT = T_DIM / 64;     // 32 kv tiles
  const size_t kstep = ((size_t)64 * B_DIM) * N1_DIM;
  size_t kb = ((size_t)r * B_DIM + b) * N1_DIM + E_DIM + h * HD_DIM + ds;

  bfrag kv0 = *(const bfrag*)(qkv + kb);
  bfrag kv1 = *(const bfrag*)(qkv + kb + 8);
  bfrag vv0 = *(const bfrag*)(qkv + kb + E_DIM);
  bfrag vv1 = *(const bfrag*)(qkv + kb + E_DIM + 8);
  *(bfrag*)&Ks[0][r][ds]     = kv0;
  *(bfrag*)&Ks[0][r][ds + 8] = kv1;
#pragma unroll
  for (int j = 0; j < 8; ++j) Vt[0][ds + j][vc0]     = vv0[j];
#pragma unroll
  for (int j = 0; j < 8; ++j) Vt[0][ds + 8 + j][vc1] = vv1[j];
  kb += kstep;
  kv0 = *(const bfrag*)(qkv + kb);
  kv1 = *(const bfrag*)(qkv + kb + 8);
  vv0 = *(const bfrag*)(qkv + kb + E_DIM);
  vv1 = *(const bfrag*)(qkv + kb + E_DIM + 8);

  for (int st = 0; st < NT; ++st) {
    const int p = st & 1;
    __syncthreads();   // buf[p] staged; all prior reads of buf[p^1] done

    f32x4 sacc[2][4];
    __builtin_amdgcn_s_setprio(1);
#pragma unroll
    for (int fs = 0; fs < 4; ++fs) {
      bfrag bk0 = *(const bfrag*)&Ks[p][fs * 16 + fr][fk];
      bfrag bk1 = *(const bfrag*)&Ks[p][fs * 16 + fr][fk + 32];
#pragma unroll
      for (int hh = 0; hh < 2; ++hh) {
        f32x4 a = f32x4{0.f, 0.f, 0.f, 0.f};
        a = mfma16(aq[hh][0], bk0, a);
        a = mfma16(aq[hh][1], bk1, a);
        sacc[hh][fs] = a;
      }
    }
    __builtin_amdgcn_s_setprio(0);

    if (st + 1 < NT) {
      *(bfrag*)&Ks[p ^ 1][r][ds]     = kv0;
      *(bfrag*)&Ks[p ^ 1][r][ds + 8] = kv1;
#pragma unroll
      for (int j = 0; j < 8; ++j) Vt[p ^ 1][ds + j][vc0]     = vv0[j];
#pragma unroll
      for (int j = 0; j < 8; ++j) Vt[p ^ 1][ds + 8 + j][vc1] = vv1[j];
    }
    if (st + 2 < NT) {
      kb += kstep;
      kv0 = *(const bfrag*)(qkv + kb);
      kv1 = *(const bfrag*)(qkv + kb + 8);
      vv0 = *(const bfrag*)(qkv + kb + E_DIM);
      vv1 = *(const bfrag*)(qkv + kb + E_DIM + 8);
    }

#pragma unroll
    for (int hh = 0; hh < 2; ++hh) {
#pragma unroll
      for (int fs = 0; fs < 4; ++fs)
#pragma unroll
        for (int rr = 0; rr < 4; ++rr)
          Ps[32 * wave + 16 * hh + cr + rr][fs * 16 + fr] = f2bf(__expf(sacc[hh][fs][rr]));

      bfrag pa0 = *(const bfrag*)&Ps[32 * wave + 16 * hh + fr][fk];
      bfrag pa1 = *(const bfrag*)&Ps[32 * wave + 16 * hh + fr][fk + 32];
      pvsum[hh] = mfma16(pa0, ones, pvsum[hh]);
      pvsum[hh] = mfma16(pa1, ones, pvsum[hh]);
      __builtin_amdgcn_s_setprio(1);
#pragma unroll
      for (int fd = 0; fd < 4; ++fd) {
        const int R = fd * 16 + fr;
        const int sg = (R >> 3) & 7;
        bfrag bv0 = *(const bfrag*)&Vt[p][R][(((fk >> 3) ^ sg) << 3)];
        bfrag bv1 = *(const bfrag*)&Vt[p][R][((((fk >> 3) + 4) ^ sg) << 3)];
        pv[hh][fd] = mfma16(pa0, bv0, pv[hh][fd]);
        pv[hh][fd] = mfma16(pa1, bv1, pv[hh][fd]);
      }
      __builtin_amdgcn_s_setprio(0);
    }
  }

#pragma unroll
  for (int hh = 0; hh < 2; ++hh)
#pragma unroll
    for (int rr = 0; rr < 4; ++rr) {
      const int row = 32 * wave + 16 * hh + cr + rr;
      const float inv = 1.0f / pvsum[hh][rr];
      if (fr == 0) linv_ws[(size_t)bh * T_DIM + t0 + row] = inv;
#pragma unroll
      for (int fd = 0; fd < 4; ++fd) {
        float v = pv[hh][fd][rr] * inv;
        int d = fd * 16 + fr;
        size_t off = ((size_t)(t0 + row) * B_DIM + b) * E_DIM + h * HD_DIM + d;
        short hi = f2bf(v);
        ctx_hi[off] = hi;
        ctx_lo[off] = f2bf(v - bf2f(hi));
      }
    }
}

// ---------------- head-averaged weights v2 ----------------
// vs round-6: Qs LDS removed (wave-own rows -> direct global, prefetched 1 head
// ahead); Ks double-buffered with reg prefetch 2 heads ahead; ONE barrier per
// head (was 2); setprio around MFMA. Same hazard pattern as attn v3.
__global__ __launch_bounds__(256) void weights_kernel(
    const short* __restrict__ qkv, const float* __restrict__ linv,
    float* __restrict__ outw)
{
  __shared__ short Ks[2][64][72];
  __shared__ float Ls[16][64];   // linv/H for 16 heads x 64 t-rows

  const int s0 = blockIdx.x * 64;
  const int bt = blockIdx.y;          // b*32 + t_tile
  const int b  = bt >> 5;
  const int t0 = (bt & 31) * 64;
  const int tid  = threadIdx.x;
  const int lane = tid & 63;
  const int wave = tid >> 6;
  const int fr = lane & 15;
  const int fk = (lane >> 4) << 3;
  const int cr = (lane >> 4) << 2;

  {
    const int hh = tid >> 4;
    const int r4 = (tid & 15) << 2;
    float4 v = *(const float4*)(linv + (size_t)(b * H_DIM + hh) * T_DIM + t0 + r4);
    Ls[hh][r4 + 0] = v.x * (1.0f / H_DIM);
    Ls[hh][r4 + 1] = v.y * (1.0f / H_DIM);
    Ls[hh][r4 + 2] = v.z * (1.0f / H_DIM);
    Ls[hh][r4 + 3] = v.w * (1.0f / H_DIM);
  }

  const int r  = tid >> 2;
  const int ds = (tid & 3) << 4;
  const size_t kb0 = ((size_t)(s0 + r) * B_DIM + b) * N1_DIM + E_DIM + ds;
  const size_t qb0 = ((size_t)(t0 + wave * 16 + fr) * B_DIM + b) * N1_DIM;

  // prologue: K(0) -> Ks[0]; K(1) -> regs; Q(0) -> regs
  {
    bfrag a0 = *(const bfrag*)(qkv + kb0);
    bfrag a1 = *(const bfrag*)(qkv + kb0 + 8);
    *(bfrag*)&Ks[0][r][ds]     = a0;
    *(bfrag*)&Ks[0][r][ds + 8] = a1;
  }
  bfrag kna = *(const bfrag*)(qkv + kb0 + HD_DIM);
  bfrag knb = *(const bfrag*)(qkv + kb0 + HD_DIM + 8);
  bfrag aq0 = *(const bfrag*)(qkv + qb0 + fk);
  bfrag aq1 = *(const bfrag*)(qkv + qb0 + fk + 32);

  f32x4 wacc[4];
#pragma unroll
  for (int i = 0; i < 4; ++i) wacc[i] = f32x4{0.f, 0.f, 0.f, 0.f};

  for (int h = 0; h < H_DIM; ++h) {
    const int p = h & 1;
    __syncthreads();   // Ks[p] staged; prior reads of Ks[p^1] done

    f32x4 sacc[4];
    __builtin_amdgcn_s_setprio(1);
#pragma unroll
    for (int fs = 0; fs < 4; ++fs) {
      bfrag bk0 = *(const bfrag*)&Ks[p][fs * 16 + fr][fk];
      bfrag bk1 = *(const bfrag*)&Ks[p][fs * 16 + fr][fk + 32];
      f32x4 a = f32x4{0.f, 0.f, 0.f, 0.f};
      a = mfma16(aq0, bk0, a);
      a = mfma16(aq1, bk1, a);
      sacc[fs] = a;
    }
    __builtin_amdgcn_s_setprio(0);

    if (h + 1 < H_DIM) {                 // stage K(h+1) from regs
      *(bfrag*)&Ks[p ^ 1][r][ds]     = kna;
      *(bfrag*)&Ks[p ^ 1][r][ds + 8] = knb;
    }
    if (h + 2 < H_DIM) {                 // prefetch K(h+2)
      kna = *(const bfrag*)(qkv + kb0 + (size_t)(h + 2) * HD_DIM);
      knb = *(const bfrag*)(qkv + kb0 + (size_t)(h + 2) * HD_DIM + 8);
    }
    if (h + 1 < H_DIM) {                 // prefetch Q(h+1) frags
      aq0 = *(const bfrag*)(qkv + qb0 + (size_t)(h + 1) * HD_DIM + fk);
      aq1 = *(const bfrag*)(qkv + qb0 + (size_t)(h + 1) * HD_DIM + fk + 32);
    }

#pragma unroll
    for (int fs = 0; fs < 4; ++fs)
#pragma unroll
      for (int rr = 0; rr < 4; ++rr)
        wacc[fs][rr] += __expf(sacc[fs][rr]) * Ls[h][wave * 16 + cr + rr];
  }

#pragma unroll
  for (int fs = 0; fs < 4; ++fs)
#pragma unroll
    for (int rr = 0; rr < 4; ++rr) {
      const int t = t0 + wave * 16 + cr + rr;
      outw[((size_t)b * T_DIM + t) * T_DIM + s0 + fs * 16 + fr] = wacc[fs][rr];
    }
}

// ---------------- host launch ----------------
extern "C" void kernel_launch(void* const* d_in, const int* in_sizes, int n_in,
                              void* d_out, int out_size, void* d_ws, size_t ws_size,
                              hipStream_t stream) {
  const float* x  = (const float*)d_in[0];   // [T,B,E]
  const float* w1 = (const float*)d_in[1];   // [3E,E]
  const float* b1 = (const float*)d_in[2];   // [3E]
  const float* w2 = (const float*)d_in[3];   // [E,E]
  const float* b2 = (const float*)d_in[4];   // [E]
  float* out = (float*)d_out;                // attn [T,B,E] then weights [B,T,T]

  char* ws = (char*)d_ws;
  size_t off = 0;
  auto carve = [&](size_t bytes) -> void* {
    void* p = ws + off;
    off = (off + bytes + 255) & ~(size_t)255;
    return p;
  };
  short* x_hi  = (short*)carve((size_t)M_DIM * E_DIM * 2);
  short* x_lo  = (short*)carve((size_t)M_DIM * E_DIM * 2);
  short* w1_hi = (short*)carve((size_t)N1_DIM * E_DIM * 2);
  short* w1_lo = (short*)carve((size_t)N1_DIM * E_DIM * 2);
  short* w2_hi = (short*)carve((size_t)E_DIM * E_DIM * 2);
  short* w2_lo = (short*)carve((size_t)E_DIM * E_DIM * 2);
  short* qkv   = (short*)carve((size_t)M_DIM * N1_DIM * 2);
  float* linv  = (float*)carve((size_t)B_DIM * H_DIM * T_DIM * 4);
  short* c_hi  = (short*)carve((size_t)M_DIM * E_DIM * 2);
  short* c_lo  = (short*)carve((size_t)M_DIM * E_DIM * 2);

  split3_kernel<<<2048, 256, 0, stream>>>(x, w1, w2, x_hi, x_lo, w1_hi, w1_lo, w2_hi, w2_lo);

  gemm_split<N1_DIM, E_DIM, true, true><<<dim3(N1_DIM / 128, M_DIM / 128), 256, 0, stream>>>(
      x_hi, x_lo, w1_hi, w1_lo, b1, (void*)qkv);

  attn_kernel<<<dim3(B_DIM * H_DIM, T_DIM / 128), 256, 0, stream>>>(
      qkv, linv, c_hi, c_lo);

  weights_kernel<<<dim3(T_DIM / 64, B_DIM * (T_DIM / 64)), 256, 0, stream>>>(
      qkv, linv, out + (size_t)M_DIM * E_DIM);

  gemm_split<E_DIM, E_DIM, false, false><<<dim3(E_DIM / 128, M_DIM / 128), 256, 0, stream>>>(
      c_hi, c_lo, w2_hi, w2_lo, b2, (void*)out);
}

// Round 10
// 336.782 us; speedup vs baseline: 1.1623x; 1.1623x over previous
//
#include <hip/hip_runtime.h>
#include <hip/hip_bf16.h>
#include <cstdint>

#define T_DIM 2048
#define B_DIM 2
#define E_DIM 1024
#define H_DIM 16
#define HD_DIM 64
#define M_DIM 4096          // T*B rows
#define N1_DIM 3072         // 3*E
#define QK_SCALE 0.125f     // HD^-0.5

typedef __attribute__((ext_vector_type(8))) short bfrag;   // 8 x bf16 (4 VGPRs)
typedef __attribute__((ext_vector_type(4))) short short4v;
typedef __attribute__((ext_vector_type(4))) float f32x4;

__device__ __forceinline__ short f2bf(float f) {
  union { float f; uint32_t u; } v; v.f = f;
  uint32_t r = v.u + 0x7fffu + ((v.u >> 16) & 1u);   // RNE
  return (short)(r >> 16);
}
__device__ __forceinline__ float bf2f(short b) {
  union { uint32_t u; float f; } v; v.u = ((uint32_t)(uint16_t)b) << 16;
  return v.f;
}
__device__ __forceinline__ f32x4 mfma16(bfrag a, bfrag b, f32x4 c) {
  return __builtin_amdgcn_mfma_f32_16x16x32_bf16(a, b, c, 0, 0, 0);
}

// ---------------- fused fp32 -> bf16 hi/lo split (x, w1, w2 in one launch) ----------------
__global__ void split3_kernel(
    const float* __restrict__ x,  const float* __restrict__ w1, const float* __restrict__ w2,
    short* __restrict__ xh,  short* __restrict__ xl,
    short* __restrict__ w1h, short* __restrict__ w1l,
    short* __restrict__ w2h, short* __restrict__ w2l)
{
  constexpr int NA = M_DIM * E_DIM;       // 4.19M
  constexpr int NB = N1_DIM * E_DIM;      // 3.15M
  constexpr int NC = E_DIM * E_DIM;       // 1.05M
  constexpr int TOT4 = (NA + NB + NC) >> 2;
  int t = blockIdx.x * blockDim.x + threadIdx.x;
  const int stride = gridDim.x * blockDim.x;
  for (; t < TOT4; t += stride) {
    int i = t << 2;
    const float* s; short* dh; short* dl;
    if (i < NA)            { s = x;  dh = xh;  dl = xl; }
    else if (i < NA + NB)  { i -= NA;       s = w1; dh = w1h; dl = w1l; }
    else                   { i -= NA + NB;  s = w2; dh = w2h; dl = w2l; }
    float4 v = *(const float4*)(s + i);
    short4v h, l;
    float vv[4] = {v.x, v.y, v.z, v.w};
#pragma unroll
    for (int c = 0; c < 4; ++c) {
      short hb = f2bf(vv[c]);
      h[c] = hb;
      l[c] = f2bf(vv[c] - bf2f(hb));
    }
    *(short4v*)(dh + i) = h;
    *(short4v*)(dl + i) = l;
  }
}

// ---------------- split-bf16 GEMM (reg-staged; round-6 measured: 98us, 789 TF) ----------------
// REVERTED from global_load_lds (round-9: 103us, FAILED — vmcnt(0)-before-barrier
// puts load latency on the critical path; reg-staged prefetch-before-barrier lets
// the compiler overlap loads with the previous iteration's MFMAs).
template<int N_T, int K_T, bool OUT_BF16, bool DO_SCALE>
__global__ __launch_bounds__(256) void gemm_split(
    const short* __restrict__ Ahi, const short* __restrict__ Alo,
    const short* __restrict__ Bhi, const short* __restrict__ Blo,
    const float* __restrict__ bias, void* __restrict__ Cout)
{
  constexpr int BK = 32;
  constexpr int LDT = BK + 8;   // pad: row stride 80B
  __shared__ short As[2][128][LDT];
  __shared__ short Bs[2][128][LDT];

  const int m0 = blockIdx.y * 128;
  const int n0 = blockIdx.x * 128;
  const int tid = threadIdx.x;
  const int lane = tid & 63;
  const int wave = tid >> 6;
  const int wr = (wave >> 1) * 64;
  const int wc = (wave & 1) * 64;

  f32x4 acc[4][4];
#pragma unroll
  for (int i = 0; i < 4; ++i)
#pragma unroll
    for (int j = 0; j < 4; ++j) acc[i][j] = f32x4{0.f, 0.f, 0.f, 0.f};

  const int ldr = tid >> 1;          // staging row 0..127
  const int ldc0 = (tid & 1) << 4;   // col 0 / 16

  for (int k0 = 0; k0 < K_T; k0 += BK) {
    const size_t aoff = (size_t)(m0 + ldr) * K_T + k0 + ldc0;
    const size_t boff = (size_t)(n0 + ldr) * K_T + k0 + ldc0;
    bfrag ah0 = *(const bfrag*)(Ahi + aoff);
    bfrag ah1 = *(const bfrag*)(Ahi + aoff + 8);
    bfrag al0 = *(const bfrag*)(Alo + aoff);
    bfrag al1 = *(const bfrag*)(Alo + aoff + 8);
    bfrag bh0 = *(const bfrag*)(Bhi + boff);
    bfrag bh1 = *(const bfrag*)(Bhi + boff + 8);
    bfrag bl0 = *(const bfrag*)(Blo + boff);
    bfrag bl1 = *(const bfrag*)(Blo + boff + 8);
    __syncthreads();   // previous iter's ds_reads done before overwrite
    *(bfrag*)&As[0][ldr][ldc0]     = ah0;
    *(bfrag*)&As[0][ldr][ldc0 + 8] = ah1;
    *(bfrag*)&As[1][ldr][ldc0]     = al0;
    *(bfrag*)&As[1][ldr][ldc0 + 8] = al1;
    *(bfrag*)&Bs[0][ldr][ldc0]     = bh0;
    *(bfrag*)&Bs[0][ldr][ldc0 + 8] = bh1;
    *(bfrag*)&Bs[1][ldr][ldc0]     = bl0;
    *(bfrag*)&Bs[1][ldr][ldc0 + 8] = bl1;
    __syncthreads();

    const int fr = lane & 15;
    const int fk = (lane >> 4) << 3;
    bfrag afh[4], afl[4];
#pragma unroll
    for (int fi = 0; fi < 4; ++fi) {
      afh[fi] = *(const bfrag*)&As[0][wr + fi * 16 + fr][fk];
      afl[fi] = *(const bfrag*)&As[1][wr + fi * 16 + fr][fk];
    }
#pragma unroll
    for (int fj = 0; fj < 4; ++fj) {
      bfrag bfh = *(const bfrag*)&Bs[0][wc + fj * 16 + fr][fk];
      bfrag bfl = *(const bfrag*)&Bs[1][wc + fj * 16 + fr][fk];
#pragma unroll
      for (int fi = 0; fi < 4; ++fi) {
        acc[fi][fj] = mfma16(afh[fi], bfh, acc[fi][fj]);
        acc[fi][fj] = mfma16(afh[fi], bfl, acc[fi][fj]);
        acc[fi][fj] = mfma16(afl[fi], bfh, acc[fi][fj]);
      }
    }
  }

  // epilogue: C/D layout col=lane&15, row=(lane>>4)*4+r  [m89]
  const int cr = (lane >> 4) << 2;
  const int cc = lane & 15;
#pragma unroll
  for (int fi = 0; fi < 4; ++fi)
#pragma unroll
    for (int fj = 0; fj < 4; ++fj)
#pragma unroll
      for (int r = 0; r < 4; ++r) {
        int m = m0 + wr + fi * 16 + cr + r;
        int n = n0 + wc + fj * 16 + cc;
        float v = acc[fi][fj][r] + bias[n];
        if (DO_SCALE) { if (n < E_DIM) v *= QK_SCALE; }   // scale q only
        if (OUT_BF16) ((short*)Cout)[(size_t)m * N_T + n] = f2bf(v);
        else          ((float*)Cout)[(size_t)m * N_T + n] = v;
      }
}

// ---------------- fused attention v3 (round-6 measured-good, unchanged) ----------------
__global__ __launch_bounds__(256) void attn_kernel(
    const short* __restrict__ qkv,   // [4096][3072] bf16 (q|k|v), q pre-scaled
    float* __restrict__ linv_ws,     // [B,H,T] reciprocal row sums
    short* __restrict__ ctx_hi, short* __restrict__ ctx_lo)  // [4096][1024]
{
  __shared__ short Ks[2][64][72];
  __shared__ short Vt[2][64][72];   // swizzled transpose
  __shared__ short Ps[128][76];

  const int bh = blockIdx.x;          // b*16 + h
  const int b  = bh >> 4;
  const int h  = bh & 15;
  const int t0 = blockIdx.y * 128;
  const int tid  = threadIdx.x;
  const int lane = tid & 63;
  const int wave = tid >> 6;
  const int fr = lane & 15;
  const int fk = (lane >> 4) << 3;
  const int cr = (lane >> 4) << 2;

  bfrag aq[2][2];
#pragma unroll
  for (int hh = 0; hh < 2; ++hh) {
    const size_t qb = ((size_t)(t0 + 32 * wave + 16 * hh + fr) * B_DIM + b) * N1_DIM + h * HD_DIM;
    aq[hh][0] = *(const bfrag*)(qkv + qb + fk);
    aq[hh][1] = *(const bfrag*)(qkv + qb + fk + 32);
  }

  bfrag ones;
#pragma unroll
  for (int j = 0; j < 8; ++j) ones[j] = (short)0x3F80;   // bf16 1.0

  f32x4 pv[2][4];
  f32x4 pvsum[2];
#pragma unroll
  for (int hh = 0; hh < 2; ++hh) {
    pvsum[hh] = f32x4{0.f, 0.f, 0.f, 0.f};
#pragma unroll
    for (int fd = 0; fd < 4; ++fd) pv[hh][fd] = f32x4{0.f, 0.f, 0.f, 0.f};
  }

  const int r  = tid >> 2;           // 0..63
  const int ds = (tid & 3) << 4;     // 0,16,32,48
  const int vc0 = (((r >> 3) ^ (ds >> 3)) << 3) | (r & 7);
  const int vc1 = (((r >> 3) ^ ((ds >> 3) + 1)) << 3) | (r & 7);

  constexpr int NT = T_DIM / 64;     // 32 kv tiles
  const size_t kstep = ((size_t)64 * B_DIM) * N1_DIM;
  size_t kb = ((size_t)r * B_DIM + b) * N1_DIM + E_DIM + h * HD_DIM + ds;

  bfrag kv0 = *(const bfrag*)(qkv + kb);
  bfrag kv1 = *(const bfrag*)(qkv + kb + 8);
  bfrag vv0 = *(const bfrag*)(qkv + kb + E_DIM);
  bfrag vv1 = *(const bfrag*)(qkv + kb + E_DIM + 8);
  *(bfrag*)&Ks[0][r][ds]     = kv0;
  *(bfrag*)&Ks[0][r][ds + 8] = kv1;
#pragma unroll
  for (int j = 0; j < 8; ++j) Vt[0][ds + j][vc0]     = vv0[j];
#pragma unroll
  for (int j = 0; j < 8; ++j) Vt[0][ds + 8 + j][vc1] = vv1[j];
  kb += kstep;
  kv0 = *(const bfrag*)(qkv + kb);
  kv1 = *(const bfrag*)(qkv + kb + 8);
  vv0 = *(const bfrag*)(qkv + kb + E_DIM);
  vv1 = *(const bfrag*)(qkv + kb + E_DIM + 8);

  for (int st = 0; st < NT; ++st) {
    const int p = st & 1;
    __syncthreads();   // buf[p] staged; all prior reads of buf[p^1] done

    f32x4 sacc[2][4];
    __builtin_amdgcn_s_setprio(1);
#pragma unroll
    for (int fs = 0; fs < 4; ++fs) {
      bfrag bk0 = *(const bfrag*)&Ks[p][fs * 16 + fr][fk];
      bfrag bk1 = *(const bfrag*)&Ks[p][fs * 16 + fr][fk + 32];
#pragma unroll
      for (int hh = 0; hh < 2; ++hh) {
        f32x4 a = f32x4{0.f, 0.f, 0.f, 0.f};
        a = mfma16(aq[hh][0], bk0, a);
        a = mfma16(aq[hh][1], bk1, a);
        sacc[hh][fs] = a;
      }
    }
    __builtin_amdgcn_s_setprio(0);

    if (st + 1 < NT) {
      *(bfrag*)&Ks[p ^ 1][r][ds]     = kv0;
      *(bfrag*)&Ks[p ^ 1][r][ds + 8] = kv1;
#pragma unroll
      for (int j = 0; j < 8; ++j) Vt[p ^ 1][ds + j][vc0]     = vv0[j];
#pragma unroll
      for (int j = 0; j < 8; ++j) Vt[p ^ 1][ds + 8 + j][vc1] = vv1[j];
    }
    if (st + 2 < NT) {
      kb += kstep;
      kv0 = *(const bfrag*)(qkv + kb);
      kv1 = *(const bfrag*)(qkv + kb + 8);
      vv0 = *(const bfrag*)(qkv + kb + E_DIM);
      vv1 = *(const bfrag*)(qkv + kb + E_DIM + 8);
    }

#pragma unroll
    for (int hh = 0; hh < 2; ++hh) {
#pragma unroll
      for (int fs = 0; fs < 4; ++fs)
#pragma unroll
        for (int rr = 0; rr < 4; ++rr)
          Ps[32 * wave + 16 * hh + cr + rr][fs * 16 + fr] = f2bf(__expf(sacc[hh][fs][rr]));

      bfrag pa0 = *(const bfrag*)&Ps[32 * wave + 16 * hh + fr][fk];
      bfrag pa1 = *(const bfrag*)&Ps[32 * wave + 16 * hh + fr][fk + 32];
      pvsum[hh] = mfma16(pa0, ones, pvsum[hh]);
      pvsum[hh] = mfma16(pa1, ones, pvsum[hh]);
      __builtin_amdgcn_s_setprio(1);
#pragma unroll
      for (int fd = 0; fd < 4; ++fd) {
        const int R = fd * 16 + fr;
        const int sg = (R >> 3) & 7;
        bfrag bv0 = *(const bfrag*)&Vt[p][R][(((fk >> 3) ^ sg) << 3)];
        bfrag bv1 = *(const bfrag*)&Vt[p][R][((((fk >> 3) + 4) ^ sg) << 3)];
        pv[hh][fd] = mfma16(pa0, bv0, pv[hh][fd]);
        pv[hh][fd] = mfma16(pa1, bv1, pv[hh][fd]);
      }
      __builtin_amdgcn_s_setprio(0);
    }
  }

#pragma unroll
  for (int hh = 0; hh < 2; ++hh)
#pragma unroll
    for (int rr = 0; rr < 4; ++rr) {
      const int row = 32 * wave + 16 * hh + cr + rr;
      const float inv = 1.0f / pvsum[hh][rr];
      if (fr == 0) linv_ws[(size_t)bh * T_DIM + t0 + row] = inv;
#pragma unroll
      for (int fd = 0; fd < 4; ++fd) {
        float v = pv[hh][fd][rr] * inv;
        int d = fd * 16 + fr;
        size_t off = ((size_t)(t0 + row) * B_DIM + b) * E_DIM + h * HD_DIM + d;
        short hi = f2bf(v);
        ctx_hi[off] = hi;
        ctx_lo[off] = f2bf(v - bf2f(hi));
      }
    }
}

// ---------------- head-averaged weights v1 (round-6 measured-good; v2 REVERTED) ----------------
__global__ __launch_bounds__(256) void weights_kernel(
    const short* __restrict__ qkv, const float* __restrict__ linv,
    float* __restrict__ outw)
{
  __shared__ short Qs[64][72];
  __shared__ short Ks[64][72];
  __shared__ float Ls[16][64];   // linv/H for 16 heads x 64 t-rows

  const int s0 = blockIdx.x * 64;
  const int bt = blockIdx.y;          // b*32 + t_tile
  const int b  = bt >> 5;
  const int t0 = (bt & 31) * 64;
  const int tid  = threadIdx.x;
  const int lane = tid & 63;
  const int wave = tid >> 6;
  const int fr = lane & 15;
  const int fk = (lane >> 4) << 3;
  const int cr = (lane >> 4) << 2;

  {
    const int hh = tid >> 4;
    const int r4 = (tid & 15) << 2;
    float4 v = *(const float4*)(linv + (size_t)(b * H_DIM + hh) * T_DIM + t0 + r4);
    Ls[hh][r4 + 0] = v.x * (1.0f / H_DIM);
    Ls[hh][r4 + 1] = v.y * (1.0f / H_DIM);
    Ls[hh][r4 + 2] = v.z * (1.0f / H_DIM);
    Ls[hh][r4 + 3] = v.w * (1.0f / H_DIM);
  }

  f32x4 wacc[4];
#pragma unroll
  for (int i = 0; i < 4; ++i) wacc[i] = f32x4{0.f, 0.f, 0.f, 0.f};

  const int r  = tid >> 2;
  const int ds = (tid & 3) << 4;

  for (int h = 0; h < H_DIM; ++h) {
    const size_t qbase = ((size_t)(t0 + r) * B_DIM + b) * N1_DIM + h * HD_DIM + ds;
    const size_t kbase = ((size_t)(s0 + r) * B_DIM + b) * N1_DIM + E_DIM + h * HD_DIM + ds;
    bfrag q0 = *(const bfrag*)(qkv + qbase);
    bfrag q1 = *(const bfrag*)(qkv + qbase + 8);
    bfrag k0 = *(const bfrag*)(qkv + kbase);
    bfrag k1 = *(const bfrag*)(qkv + kbase + 8);
    __syncthreads();   // previous head's ds_reads done (also covers Ls init)
    *(bfrag*)&Qs[r][ds]     = q0;
    *(bfrag*)&Qs[r][ds + 8] = q1;
    *(bfrag*)&Ks[r][ds]     = k0;
    *(bfrag*)&Ks[r][ds + 8] = k1;
    __syncthreads();

    bfrag aq0 = *(const bfrag*)&Qs[wave * 16 + fr][fk];
    bfrag aq1 = *(const bfrag*)&Qs[wave * 16 + fr][fk + 32];
#pragma unroll
    for (int fs = 0; fs < 4; ++fs) {
      bfrag bk0 = *(const bfrag*)&Ks[fs * 16 + fr][fk];
      bfrag bk1 = *(const bfrag*)&Ks[fs * 16 + fr][fk + 32];
      f32x4 a = f32x4{0.f, 0.f, 0.f, 0.f};
      a = mfma16(aq0, bk0, a);
      a = mfma16(aq1, bk1, a);
#pragma unroll
      for (int rr = 0; rr < 4; ++rr)
        wacc[fs][rr] += __expf(a[rr]) * Ls[h][wave * 16 + cr + rr];
    }
  }

#pragma unroll
  for (int fs = 0; fs < 4; ++fs)
#pragma unroll
    for (int rr = 0; rr < 4; ++rr) {
      const int t = t0 + wave * 16 + cr + rr;
      outw[((size_t)b * T_DIM + t) * T_DIM + s0 + fs * 16 + fr] = wacc[fs][rr];
    }
}

// ---------------- host launch ----------------
extern "C" void kernel_launch(void* const* d_in, const int* in_sizes, int n_in,
                              void* d_out, int out_size, void* d_ws, size_t ws_size,
                              hipStream_t stream) {
  const float* x  = (const float*)d_in[0];   // [T,B,E]
  const float* w1 = (const float*)d_in[1];   // [3E,E]
  const float* b1 = (const float*)d_in[2];   // [3E]
  const float* w2 = (const float*)d_in[3];   // [E,E]
  const float* b2 = (const float*)d_in[4];   // [E]
  float* out = (float*)d_out;                // attn [T,B,E] then weights [B,T,T]

  char* ws = (char*)d_ws;
  size_t off = 0;
  auto carve = [&](size_t bytes) -> void* {
    void* p = ws + off;
    off = (off + bytes + 255) & ~(size_t)255;
    return p;
  };
  short* x_hi  = (short*)carve((size_t)M_DIM * E_DIM * 2);
  short* x_lo  = (short*)carve((size_t)M_DIM * E_DIM * 2);
  short* w1_hi = (short*)carve((size_t)N1_DIM * E_DIM * 2);
  short* w1_lo = (short*)carve((size_t)N1_DIM * E_DIM * 2);
  short* w2_hi = (short*)carve((size_t)E_DIM * E_DIM * 2);
  short* w2_lo = (short*)carve((size_t)E_DIM * E_DIM * 2);
  short* qkv   = (short*)carve((size_t)M_DIM * N1_DIM * 2);
  float* linv  = (float*)carve((size_t)B_DIM * H_DIM * T_DIM * 4);
  short* c_hi  = (short*)carve((size_t)M_DIM * E_DIM * 2);
  short* c_lo  = (short*)carve((size_t)M_DIM * E_DIM * 2);

  split3_kernel<<<2048, 256, 0, stream>>>(x, w1, w2, x_hi, x_lo, w1_hi, w1_lo, w2_hi, w2_lo);

  gemm_split<N1_DIM, E_DIM, true, true><<<dim3(N1_DIM / 128, M_DIM / 128), 256, 0, stream>>>(
      x_hi, x_lo, w1_hi, w1_lo, b1, (void*)qkv);

  attn_kernel<<<dim3(B_DIM * H_DIM, T_DIM / 128), 256, 0, stream>>>(
      qkv, linv, c_hi, c_lo);

  weights_kernel<<<dim3(T_DIM / 64, B_DIM * (T_DIM / 64)), 256, 0, stream>>>(
      qkv, linv, out + (size_t)M_DIM * E_DIM);

  gemm_split<E_DIM, E_DIM, false, false><<<dim3(E_DIM / 128, M_DIM / 128), 256, 0, stream>>>(
      c_hi, c_lo, w2_hi, w2_lo, b2, (void*)out);
}